// Round 6
// baseline (185.722 us; speedup 1.0000x reference)
//
#include <hip/hip_runtime.h>
#include <math.h>

#define Bc 2
#define Tc 1024
#define Cc 1024
#define Hc 16
#define Dc 64
#define DE 128   // extended head dim (64 rope'd + 64 bias features)

typedef unsigned short u16;
typedef __attribute__((ext_vector_type(8))) short bf16x8;   // 8 bf16 in 4 VGPRs
typedef __attribute__((ext_vector_type(4))) float f32x4;

// 0.125 (1/sqrt(D)) * log2(e): prescales q so QK^T scores land in exp2 domain
#define QSCALE 0.1803368801111243f
#define FIXED_M 24.0f   // fixed softmax shift; cancels exactly in o/l

static __device__ inline u16 f2b(float f) {
    unsigned u = __float_as_uint(f);
    u = (u + 0x7fffu + ((u >> 16) & 1u)) >> 16;   // RNE to bf16
    return (u16)u;
}
static __device__ inline float b2f(u16 h) {
    return __uint_as_float((unsigned)h << 16);
}

// async global->LDS, 16B per lane; dest = wave-uniform base + lane*16
typedef __attribute__((address_space(1))) const unsigned int g_u32;
typedef __attribute__((address_space(3))) unsigned int l_u32;
static __device__ __forceinline__ void gll16(const void* g, void* l) {
    __builtin_amdgcn_global_load_lds((g_u32*)g, (l_u32*)l, 16, 0, 0);
}

// ---------------- fused cast fp32 -> bf16 for x, W_attn, W_proj ----------------
__global__ __launch_bounds__(256) void cast_all(
    const float* __restrict__ x, const float* __restrict__ wa, const float* __restrict__ wp,
    u16* __restrict__ xb, u16* __restrict__ wab, u16* __restrict__ wpb)
{
    const int NX = Bc * Tc * Cc;       // 2M
    const int NA = 3 * Cc * Cc;        // 3M
    int i = (blockIdx.x * 256 + threadIdx.x) * 4;
    const float* src; u16* dst; int off;
    if (i < NX)            { src = x;  dst = xb;  off = i; }
    else if (i < NX + NA)  { src = wa; dst = wab; off = i - NX; }
    else                   { src = wp; dst = wpb; off = i - NX - NA; }
    float4 v = *(const float4*)(src + off);
    ushort4 o;
    o.x = f2b(v.x); o.y = f2b(v.y); o.z = f2b(v.z); o.w = f2b(v.w);
    *(ushort4*)(dst + off) = o;
}

// ---------------- rope cos/sin table + bias-feature blocks ----------------
// grid (B*T), 256 threads. ctab[bt*32+m] = (cos, sin) of coord*W_rope[m].
// Also writes qe/ke cols 64..127 (t-only Fourier features, all heads).
__global__ __launch_bounds__(256) void prep_tables(
    const float* __restrict__ coords, const float* __restrict__ W_rope,
    const float* __restrict__ W_fb, const float* __restrict__ bcos,
    const float* __restrict__ bsin, float2* __restrict__ ctab,
    u16* __restrict__ qe, u16* __restrict__ ke)
{
    const int bt = blockIdx.x;
    const int b = bt >> 10;
    const int t = bt & (Tc - 1);
    const float coord = coords[bt];
    const int tid = threadIdx.x;

    if (tid < 32) {
        float th = coord * W_rope[tid];
        ctab[bt * 32 + tid] = make_float2(cosf(th), sinf(th));
    }

    // features: thread = (head hh = tid>>4, pair s = tid&15)
    const int hh = tid >> 4;
    const int s  = tid & 15;
    const int m  = 2 * s;
    float thf0 = coord * W_fb[m],     thf1 = coord * W_fb[m + 1];
    float sn0 = sinf(thf0), cn0 = cosf(thf0);
    float sn1 = sinf(thf1), cn1 = cosf(thf1);
    float bc0 = bcos[m], bs0 = bsin[m], bc1 = bcos[m + 1], bs1 = bsin[m + 1];
    const float SC = 1.41421356237f * QSCALE;
    unsigned u1 = (unsigned)f2b((bc0 * cn0 + bs0 * sn0) * SC) |
                  ((unsigned)f2b((bc1 * cn1 + bs1 * sn1) * SC) << 16);
    unsigned u2 = (unsigned)f2b((bc0 * sn0 - bs0 * cn0) * SC) |
                  ((unsigned)f2b((bc1 * sn1 - bs1 * cn1) * SC) << 16);
    unsigned cp = (unsigned)f2b(cn0) | ((unsigned)f2b(cn1) << 16);
    unsigned sp = (unsigned)f2b(sn0) | ((unsigned)f2b(sn1) << 16);
    size_t base = ((size_t)(b * Hc + hh) * Tc + t) * DE + 64;
    *(unsigned*)&qe[base + m]      = u1;
    *(unsigned*)&qe[base + 32 + m] = u2;
    *(unsigned*)&ke[base + m]      = cp;
    *(unsigned*)&ke[base + 32 + m] = sp;
}

// ---------------- C = A * B^T + bias, bf16 MFMA, double-buffered ----------------
// MODE 0: fp32 out + optional resid.  MODE 1: fused qkv epilogue -> RoPE+scatter
// into qe (prescaled), ke, vt (transposed). Rotation partner via __shfl_xor(1).
template<int TM, int TN, int WR, int WC, int MODE>
__global__ __launch_bounds__(256) void gemm_abt(
    const u16* __restrict__ A, const u16* __restrict__ Bm,
    const float* __restrict__ bias, const float* __restrict__ resid,
    float* __restrict__ outf, const float2* __restrict__ ctab,
    u16* __restrict__ qe, u16* __restrict__ ke, u16* __restrict__ vt,
    int M, int N, int K)
{
    constexpr int WTM = TM / WR;
    constexpr int WTN = TN / WC;
    constexpr int FI = WTM / 16;
    constexpr int FJ = WTN / 16;
    constexpr int ITA = TM / 32;
    constexpr int ITB = TN / 32;
    __shared__ u16 ldsA[2][TM * 64];
    __shared__ u16 ldsB[2][TN * 64];
    const int tid  = threadIdx.x;
    const int wave = tid >> 6;
    const int lane = tid & 63;
    const int l15  = lane & 15;
    const int quad = lane >> 4;
    const int wm = wave / WC;
    const int wn = wave % WC;
    const int tm = blockIdx.y * TM;
    const int tn = blockIdx.x * TN;

    f32x4 acc[FI][FJ] = {};

    auto stage = [&](int buf, int k0) {
#pragma unroll
        for (int it = 0; it < ITA; ++it) {
            int p = it * 256 + tid;
            int row = p >> 3;
            int c = ((p & 7) ^ (row & 7)) * 8;
            gll16(A + (size_t)(tm + row) * K + k0 + c,
                  &ldsA[buf][(it * 256 + (wave << 6)) * 8]);
        }
#pragma unroll
        for (int it = 0; it < ITB; ++it) {
            int p = it * 256 + tid;
            int row = p >> 3;
            int c = ((p & 7) ^ (row & 7)) * 8;
            gll16(Bm + (size_t)(tn + row) * K + k0 + c,
                  &ldsB[buf][(it * 256 + (wave << 6)) * 8]);
        }
    };

    const int NK = K >> 6;
    stage(0, 0);
    for (int ki = 0; ki < NK; ++ki) {
        const int buf = ki & 1;
        __syncthreads();                       // drains vmcnt -> buf ready for all waves
        if (ki + 1 < NK) stage(buf ^ 1, (ki + 1) << 6);
#pragma unroll
        for (int kk = 0; kk < 2; ++kk) {
            bf16x8 af[FI], bf[FJ];
#pragma unroll
            for (int i = 0; i < FI; ++i) {
                int row = wm * WTM + i * 16 + l15;
                int slot = (kk * 4 + quad) ^ (row & 7);
                af[i] = *(const bf16x8*)&ldsA[buf][row * 64 + slot * 8];
            }
#pragma unroll
            for (int j = 0; j < FJ; ++j) {
                int row = wn * WTN + j * 16 + l15;
                int slot = (kk * 4 + quad) ^ (row & 7);
                bf[j] = *(const bf16x8*)&ldsB[buf][row * 64 + slot * 8];
            }
#pragma unroll
            for (int i = 0; i < FI; ++i)
#pragma unroll
                for (int j = 0; j < FJ; ++j)
                    acc[i][j] = __builtin_amdgcn_mfma_f32_16x16x32_bf16(af[i], bf[j], acc[i][j], 0, 0, 0);
        }
    }

    if (MODE == 0) {
#pragma unroll
        for (int i = 0; i < FI; ++i) {
            int row = tm + wm * WTM + i * 16 + quad * 4;    // C/D: row = quad*4+reg
#pragma unroll
            for (int j = 0; j < FJ; ++j) {
                int col = tn + wn * WTN + j * 16 + l15;     //      col = lane&15
                float bb = bias[col];
#pragma unroll
                for (int r = 0; r < 4; ++r) {
                    float v = acc[i][j][r] + bb;
                    if (resid) v += resid[(size_t)(row + r) * N + col];
                    outf[(size_t)(row + r) * N + col] = v;
                }
            }
        }
    } else {
        const int sec = tn >> 10;   // 0=q, 1=k, 2=v (block-uniform: 128 | 1024)
#pragma unroll
        for (int i = 0; i < FI; ++i) {
#pragma unroll
            for (int r = 0; r < 4; ++r) {
                int grow = tm + wm * WTM + i * 16 + quad * 4 + r;
                int b = grow >> 10, tl = grow & (Tc - 1);
#pragma unroll
                for (int j = 0; j < FJ; ++j) {
                    int col = tn + wn * WTN + j * 16 + l15;
                    int cw = col & (Cc - 1);
                    int h = cw >> 6, d = cw & 63;
                    float v = acc[i][j][r] + bias[col];
                    if (sec == 2) {
                        vt[((size_t)(b * Hc + h) * Dc + d) * Tc + tl] = f2b(v);
                    } else {
                        float2 cs = ctab[grow * 32 + (d >> 1)];
                        float p = __shfl_xor(v, 1);
                        // even d: v*c - p*s ; odd d: p*s + v*c
                        float rot = (d & 1) ? (p * cs.y + v * cs.x)
                                            : (v * cs.x - p * cs.y);
                        if (sec == 0) {
                            qe[((size_t)(b * Hc + h) * Tc + tl) * DE + d] = f2b(rot * QSCALE);
                        } else {
                            ke[((size_t)(b * Hc + h) * Tc + tl) * DE + d] = f2b(rot);
                        }
                    }
                }
            }
        }
    }
}

// ---------------- flash attention, fixed-m softmax, explicit l reduction ----------------
// grid (T/64, H, B); 4 waves, wave owns 16 q rows; k-tile = 64, double-buffered K/V
__global__ __launch_bounds__(256) void attn_kernel(
    const u16* __restrict__ qe, const u16* __restrict__ ke,
    const u16* __restrict__ vt, u16* __restrict__ yb)
{
    __shared__ u16 ldsK[2][64 * 128];  // 32 KB, swizzled (row&15)
    __shared__ u16 ldsV[2][64 * 64];   // 16 KB, swizzled (row&7)
    __shared__ u16 plds[4][16][72];    //  9 KB wave-private P tiles
    const int tid  = threadIdx.x;
    const int wave = tid >> 6;
    const int lane = tid & 63;
    const int l15  = lane & 15;
    const int quad = lane >> 4;
    const int qt = blockIdx.x * 64;
    const int h  = blockIdx.y;
    const int b  = blockIdx.z;

    const u16* Q  = qe + ((size_t)(b * Hc + h) * Tc) * DE;
    const u16* Kp = ke + ((size_t)(b * Hc + h) * Tc) * DE;
    const u16* Vp = vt + ((size_t)(b * Hc + h) * Dc) * Tc;

    bf16x8 qf[4];
    {
        const u16* qrow = Q + (size_t)(qt + wave * 16 + l15) * DE + quad * 8;
#pragma unroll
        for (int c = 0; c < 4; ++c) qf[c] = *(const bf16x8*)(qrow + c * 32);
    }

    auto stageKV = [&](int buf, int kt) {
#pragma unroll
        for (int it = 0; it < 4; ++it) {
            int p = it * 256 + tid;
            int row = p >> 4;
            int c = (p & 15) ^ (row & 15);
            gll16(Kp + (size_t)(kt + row) * DE + c * 8,
                  &ldsK[buf][(it * 256 + (wave << 6)) * 8]);
        }
#pragma unroll
        for (int it = 0; it < 2; ++it) {
            int p = it * 256 + tid;
            int row = p >> 3;
            int c = (p & 7) ^ (row & 7);
            gll16(Vp + (size_t)row * Tc + kt + c * 8,
                  &ldsV[buf][(it * 256 + (wave << 6)) * 8]);
        }
    };

    f32x4 o[4] = {};
    float lrow[4] = {0.f, 0.f, 0.f, 0.f};

    stageKV(0, 0);
    for (int ki = 0; ki < Tc / 64; ++ki) {
        const int buf = ki & 1;
        __syncthreads();                       // buf ready (implicit vmcnt drain)
        if (ki + 1 < Tc / 64) stageKV(buf ^ 1, (ki + 1) * 64);

        f32x4 sf[4] = {};
#pragma unroll
        for (int f = 0; f < 4; ++f) {
#pragma unroll
            for (int c = 0; c < 4; ++c) {
                int row = f * 16 + l15;
                int slot = (c * 4 + quad) ^ (row & 15);
                bf16x8 kf = *(const bf16x8*)&ldsK[buf][row * 128 + slot * 8];
                sf[f] = __builtin_amdgcn_mfma_f32_16x16x32_bf16(qf[c], kf, sf[f], 0, 0, 0);
            }
        }
        // p = exp2(s - M), fixed M cancels in o/l. Truncate to bf16; l sums the
        // truncated values so softmax stays exactly normalized.
        float psum[4] = {0.f, 0.f, 0.f, 0.f};
#pragma unroll
        for (int f = 0; f < 4; ++f)
#pragma unroll
            for (int r = 0; r < 4; ++r) {
                float p = __builtin_amdgcn_exp2f(sf[f][r] - FIXED_M);
                u16 tp = (u16)(__float_as_uint(p) >> 16);
                plds[wave][quad * 4 + r][f * 16 + l15] = tp;
                psum[r] += b2f(tp);
            }
#pragma unroll
        for (int r = 0; r < 4; ++r) {
            float v = psum[r];
#pragma unroll
            for (int off = 1; off < 16; off <<= 1) v += __shfl_xor(v, off);
            lrow[r] += v;
        }

#pragma unroll
        for (int c = 0; c < 2; ++c) {
            bf16x8 pa = *(const bf16x8*)&plds[wave][l15][c * 32 + quad * 8];
#pragma unroll
            for (int df = 0; df < 4; ++df) {
                int row = df * 16 + l15;
                int slot = (c * 4 + quad) ^ (row & 7);
                bf16x8 vf = *(const bf16x8*)&ldsV[buf][row * 64 + slot * 8];
                o[df] = __builtin_amdgcn_mfma_f32_16x16x32_bf16(pa, vf, o[df], 0, 0, 0);
            }
        }
    }

    float rl[4];
#pragma unroll
    for (int r = 0; r < 4; ++r) rl[r] = 1.0f / lrow[r];
#pragma unroll
    for (int df = 0; df < 4; ++df)
#pragma unroll
        for (int r = 0; r < 4; ++r) {
            int t = qt + wave * 16 + quad * 4 + r;
            int d = df * 16 + l15;
            yb[((size_t)b * Tc + t) * Cc + h * Dc + d] = f2b(o[df][r] * rl[r]);
        }
}

extern "C" void kernel_launch(void* const* d_in, const int* in_sizes, int n_in,
                              void* d_out, int out_size, void* d_ws, size_t ws_size,
                              hipStream_t stream) {
    const float* x      = (const float*)d_in[0];
    const float* coords = (const float*)d_in[1];
    const float* W_attn = (const float*)d_in[2];
    const float* b_attn = (const float*)d_in[3];
    const float* W_proj = (const float*)d_in[4];
    const float* b_proj = (const float*)d_in[5];
    const float* W_rope = (const float*)d_in[6];
    const float* W_fb   = (const float*)d_in[7];
    const float* bcos   = (const float*)d_in[8];
    const float* bsin   = (const float*)d_in[9];
    float* out = (float*)d_out;

    char* w = (char*)d_ws;
    const size_t MB = 1024 * 1024;
    u16*    xb   = (u16*)(w + 0);          //  4 MB: x bf16
    u16*    wab  = (u16*)(w + 4 * MB);     //  6 MB: W_attn bf16
    u16*    wpb  = (u16*)(w + 10 * MB);    //  2 MB: W_proj bf16
    float2* ctab = (float2*)(w + 12 * MB); //  0.5 MB: rope cos/sin table
    u16*    qext = (u16*)(w + 13 * MB);    //  8 MB: q_ext (prescaled)
    u16*    kext = (u16*)(w + 21 * MB);    //  8 MB: k_ext
    u16*    vtw  = (u16*)(w + 29 * MB);    //  4 MB: v^T
    u16*    yb   = (u16*)(w + 33 * MB);    //  4 MB: attn out bf16

    const int NALL = (Bc * Tc * Cc + 3 * Cc * Cc + Cc * Cc) / 4;
    cast_all<<<NALL / 256, 256, 0, stream>>>(x, W_attn, W_proj, xb, wab, wpb);

    prep_tables<<<Bc * Tc, 256, 0, stream>>>(coords, W_rope, W_fb, bcos, bsin,
                                             ctab, qext, kext);

    dim3 g1(3 * Cc / 128, Bc * Tc / 128);
    gemm_abt<128, 128, 2, 2, 1><<<g1, 256, 0, stream>>>(
        xb, wab, b_attn, nullptr, nullptr, ctab, qext, kext, vtw,
        Bc * Tc, 3 * Cc, Cc);

    dim3 g2(Tc / 64, Hc, Bc);
    attn_kernel<<<g2, 256, 0, stream>>>(qext, kext, vtw, yb);

    dim3 g3(Cc / 64, Bc * Tc / 128);
    gemm_abt<128, 64, 2, 2, 0><<<g3, 256, 0, stream>>>(
        yb, wpb, b_proj, x, out, nullptr, nullptr, nullptr, nullptr,
        Bc * Tc, Cc, Cc);
}

// Round 7
// 174.696 us; speedup vs baseline: 1.0631x; 1.0631x over previous
//
#include <hip/hip_runtime.h>
#include <math.h>

#define Bc 2
#define Tc 1024
#define Cc 1024
#define Hc 16
#define Dc 64
#define DE 128   // extended head dim (64 rope'd + 64 bias features)

typedef unsigned short u16;
typedef __attribute__((ext_vector_type(8))) short bf16x8;   // 8 bf16 in 4 VGPRs
typedef __attribute__((ext_vector_type(4))) float f32x4;

// 0.125 (1/sqrt(D)) * log2(e): prescales q so QK^T scores land in exp2 domain
#define QSCALE 0.1803368801111243f
#define FIXED_M 24.0f   // fixed softmax shift; cancels exactly in o/l

static __device__ inline u16 f2b(float f) {
    unsigned u = __float_as_uint(f);
    u = (u + 0x7fffu + ((u >> 16) & 1u)) >> 16;   // RNE to bf16
    return (u16)u;
}
static __device__ inline float b2f(u16 h) {
    return __uint_as_float((unsigned)h << 16);
}

// async global->LDS, 16B per lane; dest = wave-uniform base + lane*16
typedef __attribute__((address_space(1))) const unsigned int g_u32;
typedef __attribute__((address_space(3))) unsigned int l_u32;
static __device__ __forceinline__ void gll16(const void* g, void* l) {
    __builtin_amdgcn_global_load_lds((g_u32*)g, (l_u32*)l, 16, 0, 0);
}

// ---------------- fused cast fp32 -> bf16 for x, W_attn, W_proj ----------------
__global__ __launch_bounds__(256) void cast_all(
    const float* __restrict__ x, const float* __restrict__ wa, const float* __restrict__ wp,
    u16* __restrict__ xb, u16* __restrict__ wab, u16* __restrict__ wpb)
{
    const int NX = Bc * Tc * Cc;       // 2M
    const int NA = 3 * Cc * Cc;        // 3M
    int i = (blockIdx.x * 256 + threadIdx.x) * 4;
    const float* src; u16* dst; int off;
    if (i < NX)            { src = x;  dst = xb;  off = i; }
    else if (i < NX + NA)  { src = wa; dst = wab; off = i - NX; }
    else                   { src = wp; dst = wpb; off = i - NX - NA; }
    float4 v = *(const float4*)(src + off);
    ushort4 o;
    o.x = f2b(v.x); o.y = f2b(v.y); o.z = f2b(v.z); o.w = f2b(v.w);
    *(ushort4*)(dst + off) = o;
}

// ---------------- C = A * B^T + bias (+resid), bf16 MFMA, double-buffered ----------------
template<int TM, int TN, int WR, int WC, bool OUT_BF16>
__global__ __launch_bounds__(256) void gemm_abt(
    const u16* __restrict__ A, const u16* __restrict__ Bm,
    const float* __restrict__ bias, const float* __restrict__ resid,
    float* __restrict__ outf, u16* __restrict__ outb, int M, int N, int K)
{
    constexpr int WTM = TM / WR;
    constexpr int WTN = TN / WC;
    constexpr int FI = WTM / 16;
    constexpr int FJ = WTN / 16;
    constexpr int ITA = TM / 32;
    constexpr int ITB = TN / 32;
    __shared__ u16 ldsA[2][TM * 64];
    __shared__ u16 ldsB[2][TN * 64];
    const int tid  = threadIdx.x;
    const int wave = tid >> 6;
    const int lane = tid & 63;
    const int l15  = lane & 15;
    const int quad = lane >> 4;
    const int wm = wave / WC;
    const int wn = wave % WC;
    const int tm = blockIdx.y * TM;
    const int tn = blockIdx.x * TN;

    f32x4 acc[FI][FJ] = {};

    auto stage = [&](int buf, int k0) {
#pragma unroll
        for (int it = 0; it < ITA; ++it) {
            int p = it * 256 + tid;
            int row = p >> 3;
            int c = ((p & 7) ^ (row & 7)) * 8;
            gll16(A + (size_t)(tm + row) * K + k0 + c,
                  &ldsA[buf][(it * 256 + (wave << 6)) * 8]);
        }
#pragma unroll
        for (int it = 0; it < ITB; ++it) {
            int p = it * 256 + tid;
            int row = p >> 3;
            int c = ((p & 7) ^ (row & 7)) * 8;
            gll16(Bm + (size_t)(tn + row) * K + k0 + c,
                  &ldsB[buf][(it * 256 + (wave << 6)) * 8]);
        }
    };

    const int NK = K >> 6;
    stage(0, 0);
    for (int ki = 0; ki < NK; ++ki) {
        const int buf = ki & 1;
        __syncthreads();                       // drains vmcnt -> buf ready for all waves
        if (ki + 1 < NK) stage(buf ^ 1, (ki + 1) << 6);
#pragma unroll
        for (int kk = 0; kk < 2; ++kk) {
            bf16x8 af[FI], bf[FJ];
#pragma unroll
            for (int i = 0; i < FI; ++i) {
                int row = wm * WTM + i * 16 + l15;
                int slot = (kk * 4 + quad) ^ (row & 7);
                af[i] = *(const bf16x8*)&ldsA[buf][row * 64 + slot * 8];
            }
#pragma unroll
            for (int j = 0; j < FJ; ++j) {
                int row = wn * WTN + j * 16 + l15;
                int slot = (kk * 4 + quad) ^ (row & 7);
                bf[j] = *(const bf16x8*)&ldsB[buf][row * 64 + slot * 8];
            }
#pragma unroll
            for (int i = 0; i < FI; ++i)
#pragma unroll
                for (int j = 0; j < FJ; ++j)
                    acc[i][j] = __builtin_amdgcn_mfma_f32_16x16x32_bf16(af[i], bf[j], acc[i][j], 0, 0, 0);
        }
    }

#pragma unroll
    for (int i = 0; i < FI; ++i) {
        int row = tm + wm * WTM + i * 16 + quad * 4;    // C/D: row = quad*4+reg
#pragma unroll
        for (int j = 0; j < FJ; ++j) {
            int col = tn + wn * WTN + j * 16 + l15;     //      col = lane&15
            float bb = bias[col];
#pragma unroll
            for (int r = 0; r < 4; ++r) {
                float v = acc[i][j][r] + bb;
                if (resid) v += resid[(size_t)(row + r) * N + col];
                if (OUT_BF16) outb[(size_t)(row + r) * N + col] = f2b(v);
                else          outf[(size_t)(row + r) * N + col] = v;
            }
        }
    }
}

// ---------------- RoPE + bias-feature prep (reads bf16 qkv) ----------------
__global__ __launch_bounds__(256) void prep_kernel(
    const u16* __restrict__ qkv, const float* __restrict__ coords,
    const float* __restrict__ W_rope, const float* __restrict__ W_fb,
    const float* __restrict__ bcos, const float* __restrict__ bsin,
    u16* __restrict__ qe, u16* __restrict__ ke, u16* __restrict__ vt)
{
    const int bt = blockIdx.x;
    const int b = bt >> 10;
    const int t = bt & (Tc - 1);
    const float coord = coords[bt];
    const int tid = threadIdx.x;
    const u16* row = qkv + (size_t)bt * 3072;
    const int e  = tid * 4;
    const int h  = e >> 6;
    const int d0 = e & 63;
    const int m0 = d0 >> 1;

    float th0 = coord * W_rope[m0];
    float th1 = coord * W_rope[m0 + 1];
    float s0 = sinf(th0), c0 = cosf(th0);
    float s1 = sinf(th1), c1 = cosf(th1);

    float q0 = b2f(row[e]), q1 = b2f(row[e + 1]), q2 = b2f(row[e + 2]), q3 = b2f(row[e + 3]);
    float k0 = b2f(row[1024 + e]), k1 = b2f(row[1025 + e]), k2 = b2f(row[1026 + e]), k3 = b2f(row[1027 + e]);
    float v0 = b2f(row[2048 + e]), v1 = b2f(row[2049 + e]), v2 = b2f(row[2050 + e]), v3 = b2f(row[2051 + e]);

    size_t qb = ((size_t)(b * Hc + h) * Tc + t) * DE + d0;
    // q prescaled by 0.125*log2e -> scores come out of the MFMA in exp2 domain
    qe[qb + 0] = f2b((q0 * c0 - q1 * s0) * QSCALE);
    qe[qb + 1] = f2b((q0 * s0 + q1 * c0) * QSCALE);
    qe[qb + 2] = f2b((q2 * c1 - q3 * s1) * QSCALE);
    qe[qb + 3] = f2b((q2 * s1 + q3 * c1) * QSCALE);
    ke[qb + 0] = f2b(k0 * c0 - k1 * s0);
    ke[qb + 1] = f2b(k0 * s0 + k1 * c0);
    ke[qb + 2] = f2b(k2 * c1 - k3 * s1);
    ke[qb + 3] = f2b(k2 * s1 + k3 * c1);

    size_t vb = ((size_t)(b * Hc + h) * Dc + d0) * Tc + t;
    vt[vb]          = f2b(v0);
    vt[vb + Tc]     = f2b(v1);
    vt[vb + 2 * Tc] = f2b(v2);
    vt[vb + 3 * Tc] = f2b(v3);

    // bias features, spread across all 256 threads: thread = (head hh, pair s)
    {
        const int hh = tid >> 4;
        const int s  = tid & 15;
        const int m  = 2 * s;
        float thf0 = coord * W_fb[m],     thf1 = coord * W_fb[m + 1];
        float sn0 = sinf(thf0), cn0 = cosf(thf0);
        float sn1 = sinf(thf1), cn1 = cosf(thf1);
        float bc0 = bcos[m], bs0 = bsin[m], bc1 = bcos[m + 1], bs1 = bsin[m + 1];
        const float SC = 1.41421356237f * QSCALE;
        unsigned u1 = (unsigned)f2b((bc0 * cn0 + bs0 * sn0) * SC) |
                      ((unsigned)f2b((bc1 * cn1 + bs1 * sn1) * SC) << 16);
        unsigned u2 = (unsigned)f2b((bc0 * sn0 - bs0 * cn0) * SC) |
                      ((unsigned)f2b((bc1 * sn1 - bs1 * cn1) * SC) << 16);
        unsigned cp = (unsigned)f2b(cn0) | ((unsigned)f2b(cn1) << 16);
        unsigned sp = (unsigned)f2b(sn0) | ((unsigned)f2b(sn1) << 16);
        size_t base = ((size_t)(b * Hc + hh) * Tc + t) * DE + 64;
        *(unsigned*)&qe[base + m]      = u1;
        *(unsigned*)&qe[base + 32 + m] = u2;
        *(unsigned*)&ke[base + m]      = cp;
        *(unsigned*)&ke[base + 32 + m] = sp;
    }
}

// ---------------- flash attention, fixed-m softmax, explicit l reduction ----------------
// grid (T/64, H, B); 4 waves, wave owns 16 q rows; k-tile = 64, double-buffered K/V
__global__ __launch_bounds__(256) void attn_kernel(
    const u16* __restrict__ qe, const u16* __restrict__ ke,
    const u16* __restrict__ vt, u16* __restrict__ yb)
{
    __shared__ u16 ldsK[2][64 * 128];  // 32 KB, swizzled (row&15)
    __shared__ u16 ldsV[2][64 * 64];   // 16 KB, swizzled (row&7)
    __shared__ u16 plds[4][16][72];    //  9 KB wave-private P tiles
    const int tid  = threadIdx.x;
    const int wave = tid >> 6;
    const int lane = tid & 63;
    const int l15  = lane & 15;
    const int quad = lane >> 4;
    const int qt = blockIdx.x * 64;
    const int h  = blockIdx.y;
    const int b  = blockIdx.z;

    const u16* Q  = qe + ((size_t)(b * Hc + h) * Tc) * DE;
    const u16* Kp = ke + ((size_t)(b * Hc + h) * Tc) * DE;
    const u16* Vp = vt + ((size_t)(b * Hc + h) * Dc) * Tc;

    bf16x8 qf[4];
    {
        const u16* qrow = Q + (size_t)(qt + wave * 16 + l15) * DE + quad * 8;
#pragma unroll
        for (int c = 0; c < 4; ++c) qf[c] = *(const bf16x8*)(qrow + c * 32);
    }

    auto stageKV = [&](int buf, int kt) {
#pragma unroll
        for (int it = 0; it < 4; ++it) {
            int p = it * 256 + tid;
            int row = p >> 4;
            int c = (p & 15) ^ (row & 15);
            gll16(Kp + (size_t)(kt + row) * DE + c * 8,
                  &ldsK[buf][(it * 256 + (wave << 6)) * 8]);
        }
#pragma unroll
        for (int it = 0; it < 2; ++it) {
            int p = it * 256 + tid;
            int row = p >> 3;
            int c = (p & 7) ^ (row & 7);
            gll16(Vp + (size_t)row * Tc + kt + c * 8,
                  &ldsV[buf][(it * 256 + (wave << 6)) * 8]);
        }
    };

    f32x4 o[4] = {};
    float lrow[4] = {0.f, 0.f, 0.f, 0.f};

    stageKV(0, 0);
    for (int ki = 0; ki < Tc / 64; ++ki) {
        const int buf = ki & 1;
        __syncthreads();                       // buf ready (implicit vmcnt drain)
        if (ki + 1 < Tc / 64) stageKV(buf ^ 1, (ki + 1) * 64);

        f32x4 sf[4] = {};
#pragma unroll
        for (int f = 0; f < 4; ++f) {
#pragma unroll
            for (int c = 0; c < 4; ++c) {
                int row = f * 16 + l15;
                int slot = (c * 4 + quad) ^ (row & 15);
                bf16x8 kf = *(const bf16x8*)&ldsK[buf][row * 128 + slot * 8];
                sf[f] = __builtin_amdgcn_mfma_f32_16x16x32_bf16(qf[c], kf, sf[f], 0, 0, 0);
            }
        }
        // p = exp2(s - M), fixed M cancels in o/l. Truncate to bf16; l sums the
        // truncated values so softmax stays exactly normalized.
        float psum[4] = {0.f, 0.f, 0.f, 0.f};
#pragma unroll
        for (int f = 0; f < 4; ++f)
#pragma unroll
            for (int r = 0; r < 4; ++r) {
                float p = __builtin_amdgcn_exp2f(sf[f][r] - FIXED_M);
                u16 tp = (u16)(__float_as_uint(p) >> 16);
                plds[wave][quad * 4 + r][f * 16 + l15] = tp;
                psum[r] += b2f(tp);
            }
#pragma unroll
        for (int r = 0; r < 4; ++r) {
            float v = psum[r];
#pragma unroll
            for (int off = 1; off < 16; off <<= 1) v += __shfl_xor(v, off);
            lrow[r] += v;
        }

#pragma unroll
        for (int c = 0; c < 2; ++c) {
            bf16x8 pa = *(const bf16x8*)&plds[wave][l15][c * 32 + quad * 8];
#pragma unroll
            for (int df = 0; df < 4; ++df) {
                int row = df * 16 + l15;
                int slot = (c * 4 + quad) ^ (row & 7);
                bf16x8 vf = *(const bf16x8*)&ldsV[buf][row * 64 + slot * 8];
                o[df] = __builtin_amdgcn_mfma_f32_16x16x32_bf16(pa, vf, o[df], 0, 0, 0);
            }
        }
    }

    float rl[4];
#pragma unroll
    for (int r = 0; r < 4; ++r) rl[r] = 1.0f / lrow[r];
#pragma unroll
    for (int df = 0; df < 4; ++df)
#pragma unroll
        for (int r = 0; r < 4; ++r) {
            int t = qt + wave * 16 + quad * 4 + r;
            int d = df * 16 + l15;
            yb[((size_t)b * Tc + t) * Cc + h * Dc + d] = f2b(o[df][r] * rl[r]);
        }
}

extern "C" void kernel_launch(void* const* d_in, const int* in_sizes, int n_in,
                              void* d_out, int out_size, void* d_ws, size_t ws_size,
                              hipStream_t stream) {
    const float* x      = (const float*)d_in[0];
    const float* coords = (const float*)d_in[1];
    const float* W_attn = (const float*)d_in[2];
    const float* b_attn = (const float*)d_in[3];
    const float* W_proj = (const float*)d_in[4];
    const float* b_proj = (const float*)d_in[5];
    const float* W_rope = (const float*)d_in[6];
    const float* W_fb   = (const float*)d_in[7];
    const float* bcos   = (const float*)d_in[8];
    const float* bsin   = (const float*)d_in[9];
    float* out = (float*)d_out;

    char* w = (char*)d_ws;
    const size_t MB = 1024 * 1024;
    u16* xb     = (u16*)(w + 0);          //  4 MB: x bf16
    u16* wab    = (u16*)(w + 4 * MB);     //  6 MB: W_attn bf16
    u16* wpb    = (u16*)(w + 10 * MB);    //  2 MB: W_proj bf16
    u16* qkvb16 = (u16*)(w + 12 * MB);    // 12 MB: qkv bf16
    u16* qext   = (u16*)(w + 24 * MB);    //  8 MB: q_ext (prescaled)
    u16* kext   = (u16*)(w + 32 * MB);    //  8 MB: k_ext
    u16* vtw    = (u16*)(w + 40 * MB);    //  4 MB: v^T
    u16* yb     = (u16*)(w + 44 * MB);    //  4 MB: attn out bf16

    const int NALL = (Bc * Tc * Cc + 3 * Cc * Cc + Cc * Cc) / 4;
    cast_all<<<NALL / 256, 256, 0, stream>>>(x, W_attn, W_proj, xb, wab, wpb);

    // 64x128 tile: 768 blocks = 3/CU exact, 48 KB LDS -> 3 blocks/CU resident
    dim3 g1(3 * Cc / 128, Bc * Tc / 64);
    gemm_abt<64, 128, 2, 2, true><<<g1, 256, 0, stream>>>(
        xb, wab, b_attn, nullptr, nullptr, qkvb16, Bc * Tc, 3 * Cc, Cc);

    prep_kernel<<<Bc * Tc, 256, 0, stream>>>(qkvb16, coords, W_rope, W_fb, bcos, bsin, qext, kext, vtw);

    dim3 g2(Tc / 64, Hc, Bc);
    attn_kernel<<<g2, 256, 0, stream>>>(qext, kext, vtw, yb);

    dim3 g3(Cc / 64, Bc * Tc / 64);
    gemm_abt<64, 64, 2, 2, false><<<g3, 256, 0, stream>>>(
        yb, wpb, b_proj, x, out, nullptr, Bc * Tc, Cc, Cc);
}